// Round 3
// baseline (278.218 us; speedup 1.0000x reference)
//
#include <hip/hip_runtime.h>
#include <hip/hip_bf16.h>

#define BB 8
#define CC 256
#define HH 64
#define WW 64
#define MM 512
#define HWHW 4096

typedef __attribute__((ext_vector_type(4))) float f32x4;
typedef __attribute__((ext_vector_type(8))) short s16x8;

static __device__ __forceinline__ ushort f2bf(float f) {
    unsigned u = __float_as_uint(f);
    unsigned r = ((u >> 16) & 1u) + 0x7fffu;      // RNE
    return (ushort)((u + r) >> 16);
}

static __device__ __forceinline__ void merge_top3(
        float& v0, float& v1, float& v2, int& i0, int& i1, int& i2,
        float w0, float w1, float w2, int j0, int j1, int j2) {
    float av0 = v0, av1 = v1, av2 = v2;
    int   ai0 = i0, ai1 = i1, ai2 = i2;
#define TAKE(OV, OI)                                                         \
    {                                                                        \
        bool ta = (av0 > w0) || (av0 == w0 && ai0 < j0);                     \
        OV = ta ? av0 : w0; OI = ta ? ai0 : j0;                              \
        if (ta) { av0 = av1; ai0 = ai1; av1 = av2; ai1 = ai2;                \
                  av2 = -3e38f; ai2 = 0x7fffffff; }                          \
        else    { w0 = w1; j0 = j1; w1 = w2; j1 = j2;                        \
                  w2 = -3e38f; j2 = 0x7fffffff; }                            \
    }
    TAKE(v0, i0); TAKE(v1, i1); TAKE(v2, i2);
#undef TAKE
}

// ---------------- K1: I_G = mean over H,W ----------------
__global__ void k_ig(const float* __restrict__ img, float* __restrict__ IG) {
    int bc = blockIdx.x;
    const float4* p = (const float4*)(img + (size_t)bc * HWHW);
    int t = threadIdx.x;
    float s = 0.f;
#pragma unroll
    for (int k = 0; k < 4; k++) {
        float4 v = p[t + 256 * k];
        s += v.x + v.y + v.z + v.w;
    }
#pragma unroll
    for (int off = 32; off > 0; off >>= 1) s += __shfl_down(s, off);
    __shared__ float red[4];
    int wave = t >> 6, lane = t & 63;
    if (lane == 0) red[wave] = s;
    __syncthreads();
    if (t == 0) IG[bc] = (red[0] + red[1] + red[2] + red[3]) * (1.f / 4096.f);
}

// ---------------- K2: gate g = sigmoid(softmax(IG@M^T)@M + IG) ----------------
__global__ void k_global(const float* __restrict__ IG, const float* __restrict__ mem,
                         float* __restrict__ g) {
    int b = blockIdx.x;
    int t = threadIdx.x;
    __shared__ float ig[CC];
    __shared__ float sc[MM];
    __shared__ float red[256];
    ig[t] = IG[b * CC + t];
    __syncthreads();
#pragma unroll
    for (int half = 0; half < 2; half++) {
        int m = t + half * 256;
        const float4* mr = (const float4*)(mem + (size_t)m * CC);
        const float4* igr = (const float4*)ig;
        float s0 = 0.f, s1 = 0.f, s2 = 0.f, s3 = 0.f;
#pragma unroll 8
        for (int ci = 0; ci < 64; ci++) {
            float4 mv = mr[ci];
            float4 iv = igr[ci];
            s0 = fmaf(mv.x, iv.x, s0); s1 = fmaf(mv.y, iv.y, s1);
            s2 = fmaf(mv.z, iv.z, s2); s3 = fmaf(mv.w, iv.w, s3);
        }
        sc[m] = (s0 + s1) + (s2 + s3);
    }
    __syncthreads();
    red[t] = fmaxf(sc[t], sc[t + 256]);
    __syncthreads();
    for (int o = 128; o > 0; o >>= 1) {
        if (t < o) red[t] = fmaxf(red[t], red[t + o]);
        __syncthreads();
    }
    float mx = red[0];
    __syncthreads();
    float e0 = expf(sc[t] - mx), e1 = expf(sc[t + 256] - mx);
    red[t] = e0 + e1;
    __syncthreads();
    for (int o = 128; o > 0; o >>= 1) {
        if (t < o) red[t] += red[t + o];
        __syncthreads();
    }
    float inv = 1.f / red[0];
    sc[t] = e0 * inv; sc[t + 256] = e1 * inv;
    __syncthreads();
    float r0 = ig[t], r1 = 0.f, r2 = 0.f, r3 = 0.f;
#pragma unroll 8
    for (int m = 0; m < MM; m += 4) {
        r0 = fmaf(sc[m + 0], mem[(size_t)(m + 0) * CC + t], r0);
        r1 = fmaf(sc[m + 1], mem[(size_t)(m + 1) * CC + t], r1);
        r2 = fmaf(sc[m + 2], mem[(size_t)(m + 2) * CC + t], r2);
        r3 = fmaf(sc[m + 3], mem[(size_t)(m + 3) * CC + t], r3);
    }
    float r = (r0 + r1) + (r2 + r3);
    g[b * CC + t] = 1.f / (1.f + expf(-r));
}

// ---------------- K3: membf[m][c] = bf16(memory[m][c]) ----------------
__global__ void k_prep(const float* __restrict__ mem, ushort* __restrict__ membf) {
    int i = (blockIdx.x * 256 + threadIdx.x) * 4;
    float4 v = *(const float4*)(mem + i);
    ushort4 o;
    o.x = f2bf(v.x); o.y = f2bf(v.y); o.z = f2bf(v.z); o.w = f2bf(v.w);
    *(ushort4*)(membf + i) = o;
}

// ---------------- K4: mf[m][o] = sum_c memory[m][c] * fusion_w[o][256+c] (fp32) ------
__global__ void k_mf(const float* __restrict__ mem, const float* __restrict__ fw,
                     float* __restrict__ mf) {
    int m0 = blockIdx.x * 8;
    int t = threadIdx.x;
    __shared__ float mrow[8][CC];
#pragma unroll
    for (int j = 0; j < 8; j++) mrow[j][t] = mem[(size_t)(m0 + j) * CC + t];
    __syncthreads();
    const float4* fwr = (const float4*)(fw + (size_t)t * (2 * CC) + CC);
    float acc[8];
#pragma unroll
    for (int j = 0; j < 8; j++) acc[j] = 0.f;
#pragma unroll 8
    for (int ci = 0; ci < 64; ci++) {
        float4 fv = fwr[ci];
#pragma unroll
        for (int j = 0; j < 8; j++) {
            acc[j] = fmaf(mrow[j][ci * 4 + 0], fv.x, acc[j]);
            acc[j] = fmaf(mrow[j][ci * 4 + 1], fv.y, acc[j]);
            acc[j] = fmaf(mrow[j][ci * 4 + 2], fv.z, acc[j]);
            acc[j] = fmaf(mrow[j][ci * 4 + 3], fv.w, acc[j]);
        }
    }
#pragma unroll
    for (int j = 0; j < 8; j++) mf[(size_t)(m0 + j) * CC + t] = acc[j];
}

// ---------------- K5: Wgbf[b][o][c] = bf16(g[b][c] * fusion_w[o][c]) ----------------
__global__ void k_wgbf(const float* __restrict__ g, const float* __restrict__ fw,
                       ushort* __restrict__ Wgbf) {
    int b = blockIdx.x >> 8, o = blockIdx.x & 255;
    int c = threadIdx.x;
    Wgbf[((size_t)blockIdx.x << 8) + c] = f2bf(g[(b << 8) + c] * fw[o * (2 * CC) + c]);
}

// ---------------- K6: main fused kernel (MFMA, m-split across waves) ----------------
// grid 512 = B*H ; block 256 = 4 waves; block owns one image row (64 px).
// Wave w owns m in [128w,128w+128) (phase A) / o in [64w,64w+64) (phase B), ALL 64 px.
// Lane (pxl=lane&15, g16=lane>>4); k-mapping: group g16 holds k=ks*32+8*g16..+8
// (same bijection on A and B); C/D: col=lane&15, row=4*(lane>>4)+reg [verified].
__global__ __launch_bounds__(256, 2) void k_main(
        const float* __restrict__ img, const float* __restrict__ mem,
        const ushort* __restrict__ membf, const ushort* __restrict__ Wgbf,
        const float* __restrict__ mf, const float* __restrict__ fb,
        float* __restrict__ xbuf) {
    int bh = blockIdx.x;
    int b = bh >> 6, h = bh & 63;
    int t = threadIdx.x;
    int wave = __builtin_amdgcn_readfirstlane(t) >> 6;
    int lane = t & 63;
    int pxl  = lane & 15;
    int g16  = lane >> 4;

    __shared__ float Xs[CC][64];        // 64 KB
    __shared__ float wtk_v[4][64][3];   // 3 KB
    __shared__ int   wtk_i[4][64][3];   // 3 KB
    __shared__ float rsv[4][64];        // 1 KB
    __shared__ int   dsi[4][64];        // 1 KB
    __shared__ float att_a[2][64];
    __shared__ int   att_b[2][64];

    // ---- stage X tile [256 c][64 w] fp32 ----
    const float* src = img + (size_t)b * CC * HWHW + h * 64;
#pragma unroll
    for (int pass = 0; pass < 16; pass++) {
        int c = pass * 16 + (t >> 4);
        int w4 = (t & 15) * 4;
        *(float4*)&Xs[c][w4] = *(const float4*)(src + (size_t)c * HWHW + w4);
    }
    __syncthreads();

    // ---- bf16 B-fragments for ALL 4 pixel tiles (reused by both GEMMs) ----
    s16x8 bfr[4][8];
#pragma unroll
    for (int pt = 0; pt < 4; pt++)
#pragma unroll
        for (int ks = 0; ks < 8; ks++) {
            s16x8 v;
#pragma unroll
            for (int j = 0; j < 8; j++)
                v[j] = (short)f2bf(Xs[ks * 32 + g16 * 8 + j][pt * 16 + pxl]);
            bfr[pt][ks] = v;
        }

    // ---- phase A: wave's 128 m x 64 px scores; per-lane top-3 per pixel slot ----
    float tv[4][3];
    int   ti[4][3];
#pragma unroll
    for (int pt = 0; pt < 4; pt++)
#pragma unroll
        for (int q = 0; q < 3; q++) { tv[pt][q] = -3e38f; ti[pt][q] = 0x7fffffff; }

    for (int mt = 0; mt < 8; mt++) {
        int m0 = wave * 128 + mt * 16;
        const ushort* arow = membf + (size_t)(m0 + pxl) * CC + g16 * 8;
        s16x8 af[8];
#pragma unroll
        for (int ks = 0; ks < 8; ks++) af[ks] = *(const s16x8*)(arow + ks * 32);
#pragma unroll
        for (int pt = 0; pt < 4; pt++) {
            f32x4 acc = {0.f, 0.f, 0.f, 0.f};
#pragma unroll
            for (int ks = 0; ks < 8; ks++)
                acc = __builtin_amdgcn_mfma_f32_16x16x32_bf16(af[ks], bfr[pt][ks], acc, 0, 0, 0);
#pragma unroll
            for (int r = 0; r < 4; r++) {
                float s = acc[r];
                int m = m0 + 4 * g16 + r;           // ascending per lane -> stable ties
                if (s > tv[pt][2]) {
                    if (s > tv[pt][1]) {
                        if (s > tv[pt][0]) {
                            tv[pt][2] = tv[pt][1]; ti[pt][2] = ti[pt][1];
                            tv[pt][1] = tv[pt][0]; ti[pt][1] = ti[pt][0];
                            tv[pt][0] = s;          ti[pt][0] = m;
                        } else {
                            tv[pt][2] = tv[pt][1]; ti[pt][2] = ti[pt][1];
                            tv[pt][1] = s;          ti[pt][1] = m;
                        }
                    } else { tv[pt][2] = s; ti[pt][2] = m; }
                }
            }
        }
    }

    // ---- butterfly merge across g16 groups -> wave top-3 per pixel ----
#pragma unroll
    for (int step = 0; step < 2; step++) {
        int d = 16 << step;
#pragma unroll
        for (int pt = 0; pt < 4; pt++) {
            float w0 = __shfl_xor(tv[pt][0], d, 64);
            float w1 = __shfl_xor(tv[pt][1], d, 64);
            float w2 = __shfl_xor(tv[pt][2], d, 64);
            int   j0 = __shfl_xor(ti[pt][0], d, 64);
            int   j1 = __shfl_xor(ti[pt][1], d, 64);
            int   j2 = __shfl_xor(ti[pt][2], d, 64);
            merge_top3(tv[pt][0], tv[pt][1], tv[pt][2],
                       ti[pt][0], ti[pt][1], ti[pt][2], w0, w1, w2, j0, j1, j2);
        }
    }
    // lane l writes its pt==g16 slot: px == lane
#pragma unroll
    for (int q = 0; q < 3; q++) {
        float v = (g16 == 0) ? tv[0][q] : (g16 == 1) ? tv[1][q] : (g16 == 2) ? tv[2][q] : tv[3][q];
        int   i = (g16 == 0) ? ti[0][q] : (g16 == 1) ? ti[1][q] : (g16 == 2) ? ti[2][q] : ti[3][q];
        wtk_v[wave][lane][q] = v;
        wtk_i[wave][lane][q] = i;
    }
    __syncthreads();

    // ---- merge 12 -> top-4 candidates; fp32 rescore (thread = cnd*64 + px) ----
    {
        int cnd = t >> 6;
        int px  = t & 63;
        float c0 = -3e38f, c1 = -3e38f, c2 = -3e38f, c3 = -3e38f;
        int   d0 = 0, d1 = 0, d2 = 0, d3 = 0;
#pragma unroll
        for (int wv = 0; wv < 4; wv++)
#pragma unroll
            for (int q = 0; q < 3; q++) {
                float s = wtk_v[wv][px][q];
                int m = wtk_i[wv][px][q];
                if (s > c3) {
                    if (s > c1) {
                        if (s > c0) { c3 = c2; d3 = d2; c2 = c1; d2 = d1; c1 = c0; d1 = d0; c0 = s; d0 = m; }
                        else        { c3 = c2; d3 = d2; c2 = c1; d2 = d1; c1 = s;  d1 = m; }
                    } else {
                        if (s > c2) { c3 = c2; d3 = d2; c2 = s;  d2 = m; }
                        else        { c3 = s;  d3 = m; }
                    }
                }
            }
        int cand = (cnd == 0) ? d0 : (cnd == 1) ? d1 : (cnd == 2) ? d2 : d3;
        const float4* mr = (const float4*)(mem + (size_t)cand * CC);
        float sa = 0.f;
#pragma unroll 4
        for (int ci = 0; ci < 64; ci++) {
            float4 mv = mr[ci];
            sa = fmaf(Xs[ci * 4 + 0][px], mv.x, sa);
            sa = fmaf(Xs[ci * 4 + 1][px], mv.y, sa);
            sa = fmaf(Xs[ci * 4 + 2][px], mv.z, sa);
            sa = fmaf(Xs[ci * 4 + 3][px], mv.w, sa);
        }
        rsv[cnd][px] = sa;
        dsi[cnd][px] = cand;
    }
    __syncthreads();

    // ---- top-2 of 4 rescored + softmax -> att (wave 0 only) ----
    if (t < 64) {
        float s0 = -3e38f, s1 = -3e38f;
        int   b0 = 0, b1 = 0;
#pragma unroll
        for (int q = 0; q < 4; q++) {
            float s = rsv[q][t];
            int m = dsi[q][t];
            if (s > s1) {
                if (s > s0) { s1 = s0; b1 = b0; s0 = s; b0 = m; }
                else        { s1 = s;  b1 = m; }
            }
        }
        float e = expf(s1 - s0);
        float ia = 1.f / (1.f + e);
        att_a[0][t] = ia;
        att_a[1][t] = e * ia;
        att_b[0][t] = b0;
        att_b[1][t] = b1;
    }
    __syncthreads();

    // ---- phase B: wave's 64 o x 64 px fusion GEMM + epilogue ----
    const ushort* wgb = Wgbf + (size_t)b * CC * CC;
    for (int ot = 0; ot < 4; ot++) {
        int o0 = wave * 64 + ot * 16;
        const ushort* arow = wgb + (size_t)(o0 + pxl) * CC + g16 * 8;
        s16x8 af[8];
#pragma unroll
        for (int ks = 0; ks < 8; ks++) af[ks] = *(const s16x8*)(arow + ks * 32);
        int ob = o0 + 4 * g16;
        float4 fbv = *(const float4*)(fb + ob);
#pragma unroll
        for (int pt = 0; pt < 4; pt++) {
            f32x4 acc = {0.f, 0.f, 0.f, 0.f};
#pragma unroll
            for (int ks = 0; ks < 8; ks++)
                acc = __builtin_amdgcn_mfma_f32_16x16x32_bf16(af[ks], bfr[pt][ks], acc, 0, 0, 0);
            int px = pt * 16 + pxl;
            float a0 = att_a[0][px], a1 = att_a[1][px];
            int   b0 = att_b[0][px], b1 = att_b[1][px];
            float4 m0v = *(const float4*)(mf + (size_t)b0 * CC + ob);
            float4 m1v = *(const float4*)(mf + (size_t)b1 * CC + ob);
#pragma unroll
            for (int r = 0; r < 4; r++) {
                float mr0 = (r == 0) ? m0v.x : (r == 1) ? m0v.y : (r == 2) ? m0v.z : m0v.w;
                float mr1 = (r == 0) ? m1v.x : (r == 1) ? m1v.y : (r == 2) ? m1v.z : m1v.w;
                float fbr = (r == 0) ? fbv.x : (r == 1) ? fbv.y : (r == 2) ? fbv.z : fbv.w;
                float val = acc[r] + a0 * mr0 + a1 * mr1 + fbr;
                val = val > 0.f ? val : 0.2f * val;
                xbuf[((size_t)(b * CC + ob + r)) * HWHW + h * 64 + px] = val;
            }
        }
    }
}

// ---------------- K7: depthwise dilated 3x3 (d=2) + bias + leaky ----------------
__global__ void k_dw(const float* __restrict__ x, const float* __restrict__ dw,
                     const float* __restrict__ db, float* __restrict__ out) {
    int bc = blockIdx.x;
    int c = bc & 255;
    __shared__ float plane[HWHW];
    const float4* src = (const float4*)(x + (size_t)bc * HWHW);
    int t = threadIdx.x;
#pragma unroll
    for (int k = 0; k < 4; k++) ((float4*)plane)[t + 256 * k] = src[t + 256 * k];
    __syncthreads();
    float w[9];
#pragma unroll
    for (int j = 0; j < 9; j++) w[j] = dw[c * 9 + j];
    float bias = db[c];
    float* dst = out + (size_t)bc * HWHW;
#pragma unroll
    for (int k = 0; k < 16; k++) {
        int p = t + 256 * k;
        int hh = p >> 6, ww = p & 63;
        float s = bias;
#pragma unroll
        for (int u = 0; u < 3; u++) {
            int h2 = hh + 2 * (u - 1);
            if ((unsigned)h2 < 64u) {
#pragma unroll
                for (int v = 0; v < 3; v++) {
                    int w2 = ww + 2 * (v - 1);
                    if ((unsigned)w2 < 64u) s = fmaf(plane[h2 * 64 + w2], w[u * 3 + v], s);
                }
            }
        }
        dst[p] = s > 0.f ? s : 0.2f * s;
    }
}

extern "C" void kernel_launch(void* const* d_in, const int* in_sizes, int n_in,
                              void* d_out, int out_size, void* d_ws, size_t ws_size,
                              hipStream_t stream) {
    const float* img = (const float*)d_in[0];
    const float* mem = (const float*)d_in[1];
    const float* fw  = (const float*)d_in[2];
    const float* fb  = (const float*)d_in[3];
    const float* dw  = (const float*)d_in[4];
    const float* db  = (const float*)d_in[5];
    float* out = (float*)d_out;
    float* ws = (float*)d_ws;

    float*  IG    = ws;                                   // 2048
    float*  gbuf  = ws + 2048;                            // 2048
    float*  mf    = ws + 4096;                            // 131072
    ushort* membf = (ushort*)(ws + 135168);               // 131072 u16
    ushort* Wgbf  = (ushort*)(ws + 135168 + 65536);       // 524288 u16
    float*  xb    = ws + 135168 + 65536 + 262144;         // 8388608 f32

    k_ig    <<<BB * CC, 256, 0, stream>>>(img, IG);
    k_prep  <<<128,     256, 0, stream>>>(mem, membf);
    k_mf    <<<MM / 8,  256, 0, stream>>>(mem, fw, mf);
    k_global<<<BB,      256, 0, stream>>>(IG, mem, gbuf);
    k_wgbf  <<<BB * CC, 256, 0, stream>>>(gbuf, fw, Wgbf);
    k_main  <<<BB * HH, 256, 0, stream>>>(img, mem, membf, Wgbf, mf, fb, xb);
    k_dw    <<<BB * CC, 256, 0, stream>>>(xb, dw, db, out);
}

// Round 4
// 260.267 us; speedup vs baseline: 1.0690x; 1.0690x over previous
//
#include <hip/hip_runtime.h>
#include <hip/hip_bf16.h>

#define BB 8
#define CC 256
#define HH 64
#define WW 64
#define MM 512
#define HWHW 4096

typedef __attribute__((ext_vector_type(4))) float f32x4;
typedef __attribute__((ext_vector_type(8))) short s16x8;

static __device__ __forceinline__ ushort f2bf(float f) {
    unsigned u = __float_as_uint(f);
    unsigned r = ((u >> 16) & 1u) + 0x7fffu;      // RNE
    return (ushort)((u + r) >> 16);
}

// ---------------- K_pre: fused {ig | prep | mf} ----------------
// bid < 2048          : ig    (I_G = mean over H,W)
// 2048 <= bid < 2176  : prep  (membf = bf16(memory))
// 2176 <= bid < 2240  : mf    (mf[m][o] = sum_c mem[m][c]*fw[o][256+c])
__global__ void k_pre(const float* __restrict__ img, const float* __restrict__ mem,
                      const float* __restrict__ fw, float* __restrict__ IG,
                      ushort* __restrict__ membf, float* __restrict__ mf) {
    int bid = blockIdx.x;
    int t = threadIdx.x;
    if (bid < 2048) {
        const float4* p = (const float4*)(img + (size_t)bid * HWHW);
        float s = 0.f;
#pragma unroll
        for (int k = 0; k < 4; k++) {
            float4 v = p[t + 256 * k];
            s += v.x + v.y + v.z + v.w;
        }
#pragma unroll
        for (int off = 32; off > 0; off >>= 1) s += __shfl_down(s, off);
        __shared__ float red[4];
        int wave = t >> 6, lane = t & 63;
        if (lane == 0) red[wave] = s;
        __syncthreads();
        if (t == 0) IG[bid] = (red[0] + red[1] + red[2] + red[3]) * (1.f / 4096.f);
    } else if (bid < 2176) {
        int i = ((bid - 2048) * 256 + t) * 4;
        float4 v = *(const float4*)(mem + i);
        ushort4 o;
        o.x = f2bf(v.x); o.y = f2bf(v.y); o.z = f2bf(v.z); o.w = f2bf(v.w);
        *(ushort4*)(membf + i) = o;
    } else {
        int m0 = (bid - 2176) * 8;
        __shared__ float mrow[8][CC];
#pragma unroll
        for (int j = 0; j < 8; j++) mrow[j][t] = mem[(size_t)(m0 + j) * CC + t];
        __syncthreads();
        const float4* fwr = (const float4*)(fw + (size_t)t * (2 * CC) + CC);
        float acc[8];
#pragma unroll
        for (int j = 0; j < 8; j++) acc[j] = 0.f;
#pragma unroll 8
        for (int ci = 0; ci < 64; ci++) {
            float4 fv = fwr[ci];
#pragma unroll
            for (int j = 0; j < 8; j++) {
                acc[j] = fmaf(mrow[j][ci * 4 + 0], fv.x, acc[j]);
                acc[j] = fmaf(mrow[j][ci * 4 + 1], fv.y, acc[j]);
                acc[j] = fmaf(mrow[j][ci * 4 + 2], fv.z, acc[j]);
                acc[j] = fmaf(mrow[j][ci * 4 + 3], fv.w, acc[j]);
            }
        }
#pragma unroll
        for (int j = 0; j < 8; j++) mf[(size_t)(m0 + j) * CC + t] = acc[j];
    }
}

// ---------------- K2: gate g = sigmoid(softmax(IG@M^T)@M + IG) ----------------
__global__ void k_global(const float* __restrict__ IG, const float* __restrict__ mem,
                         float* __restrict__ g) {
    int b = blockIdx.x;
    int t = threadIdx.x;
    __shared__ float ig[CC];
    __shared__ float sc[MM];
    __shared__ float red[256];
    ig[t] = IG[b * CC + t];
    __syncthreads();
#pragma unroll
    for (int half = 0; half < 2; half++) {
        int m = t + half * 256;
        const float4* mr = (const float4*)(mem + (size_t)m * CC);
        const float4* igr = (const float4*)ig;
        float s0 = 0.f, s1 = 0.f, s2 = 0.f, s3 = 0.f;
#pragma unroll 8
        for (int ci = 0; ci < 64; ci++) {
            float4 mv = mr[ci];
            float4 iv = igr[ci];
            s0 = fmaf(mv.x, iv.x, s0); s1 = fmaf(mv.y, iv.y, s1);
            s2 = fmaf(mv.z, iv.z, s2); s3 = fmaf(mv.w, iv.w, s3);
        }
        sc[m] = (s0 + s1) + (s2 + s3);
    }
    __syncthreads();
    red[t] = fmaxf(sc[t], sc[t + 256]);
    __syncthreads();
    for (int o = 128; o > 0; o >>= 1) {
        if (t < o) red[t] = fmaxf(red[t], red[t + o]);
        __syncthreads();
    }
    float mx = red[0];
    __syncthreads();
    float e0 = expf(sc[t] - mx), e1 = expf(sc[t + 256] - mx);
    red[t] = e0 + e1;
    __syncthreads();
    for (int o = 128; o > 0; o >>= 1) {
        if (t < o) red[t] += red[t + o];
        __syncthreads();
    }
    float inv = 1.f / red[0];
    sc[t] = e0 * inv; sc[t + 256] = e1 * inv;
    __syncthreads();
    float r0 = ig[t], r1 = 0.f, r2 = 0.f, r3 = 0.f;
#pragma unroll 8
    for (int m = 0; m < MM; m += 4) {
        r0 = fmaf(sc[m + 0], mem[(size_t)(m + 0) * CC + t], r0);
        r1 = fmaf(sc[m + 1], mem[(size_t)(m + 1) * CC + t], r1);
        r2 = fmaf(sc[m + 2], mem[(size_t)(m + 2) * CC + t], r2);
        r3 = fmaf(sc[m + 3], mem[(size_t)(m + 3) * CC + t], r3);
    }
    float r = (r0 + r1) + (r2 + r3);
    g[b * CC + t] = 1.f / (1.f + expf(-r));
}

// ---------------- K5: Wgbf[b][o][c] = bf16(g[b][c] * fusion_w[o][c]) ----------------
__global__ void k_wgbf(const float* __restrict__ g, const float* __restrict__ fw,
                       ushort* __restrict__ Wgbf) {
    int b = blockIdx.x >> 8, o = blockIdx.x & 255;
    int c = threadIdx.x;
    Wgbf[((size_t)blockIdx.x << 8) + c] = f2bf(g[(b << 8) + c] * fw[o * (2 * CC) + c]);
}

// ---------------- K6: main fused kernel (MFMA; round-2 structure + prefetch) -------
// grid 512 = B*H ; block 256 (4 waves); one image row (64 px) per block.
// wave w owns pixels [16w,16w+16) and streams ALL 512 m / 256 o for them.
// k-mapping: lane-group g16 holds k=ks*32+8*g16..+8 (same bijection on A and B);
// C/D: col=lane&15, row=4*(lane>>4)+reg [verified].
__global__ __launch_bounds__(256, 2) void k_main(
        const float* __restrict__ img, const float* __restrict__ mem,
        const ushort* __restrict__ membf, const ushort* __restrict__ Wgbf,
        const float* __restrict__ mf, const float* __restrict__ fb,
        float* __restrict__ xbuf) {
    int bh = blockIdx.x;
    int b = bh >> 6, h = bh & 63;
    int t = threadIdx.x;
    int wave = __builtin_amdgcn_readfirstlane(t) >> 6;
    int lane = t & 63;
    int pxl  = lane & 15;
    int g16  = lane >> 4;
    int pxw  = wave * 16 + pxl;

    __shared__ float Xs[CC][64];        // 64 KB
    __shared__ float tkv[4][16][12];
    __shared__ int   tki[4][16][12];
    __shared__ float rsv[4][16][4];

    // ---- stage X tile [256 c][64 w] fp32 ----
    const float* src = img + (size_t)b * CC * HWHW + h * 64;
#pragma unroll
    for (int pass = 0; pass < 16; pass++) {
        int c = pass * 16 + (t >> 4);
        int w4 = (t & 15) * 4;
        *(float4*)&Xs[c][w4] = *(const float4*)(src + (size_t)c * HWHW + w4);
    }
    __syncthreads();

    // ---- bf16 B-fragments for this wave's 16 pixels (reused by both GEMMs) ----
    s16x8 bfr[8];
#pragma unroll
    for (int ks = 0; ks < 8; ks++) {
        s16x8 v;
#pragma unroll
        for (int j = 0; j < 8; j++)
            v[j] = (short)f2bf(Xs[ks * 32 + g16 * 8 + j][pxw]);
        bfr[ks] = v;
    }

    // ---- phase A: 512 m x 16 px scores, double-buffered A prefetch ----
    float v0 = -3e38f, v1 = -3e38f, v2 = -3e38f;
    int   i0 = 0, i1 = 0, i2 = 0;
#define TOPK_UPDATE(ACC, MT)                                                   \
    {                                                                          \
        _Pragma("unroll")                                                      \
        for (int r = 0; r < 4; r++) {                                          \
            float s = (ACC)[r];                                                \
            int m = (MT) * 16 + 4 * g16 + r;                                   \
            if (s > v2) {                                                      \
                if (s > v1) {                                                  \
                    if (s > v0) { v2 = v1; i2 = i1; v1 = v0; i1 = i0;          \
                                  v0 = s;  i0 = m; }                           \
                    else        { v2 = v1; i2 = i1; v1 = s;  i1 = m; }         \
                } else          { v2 = s;  i2 = m; }                           \
            }                                                                  \
        }                                                                      \
    }
#define MFMA8(AF, ACC)                                                         \
    {                                                                          \
        _Pragma("unroll")                                                      \
        for (int ks = 0; ks < 8; ks++)                                         \
            ACC = __builtin_amdgcn_mfma_f32_16x16x32_bf16((AF)[ks], bfr[ks],   \
                                                          ACC, 0, 0, 0);       \
    }
    {
        const ushort* aptr = membf + (size_t)pxl * CC + g16 * 8;
        s16x8 afA[8], afB[8];
#pragma unroll
        for (int ks = 0; ks < 8; ks++) afA[ks] = *(const s16x8*)(aptr + ks * 32);
        for (int mt = 0; mt < 32; mt += 2) {
            const ushort* pB = aptr + (size_t)(mt + 1) * 16 * CC;
#pragma unroll
            for (int ks = 0; ks < 8; ks++) afB[ks] = *(const s16x8*)(pB + ks * 32);
            f32x4 accA = {0.f, 0.f, 0.f, 0.f};
            MFMA8(afA, accA);
            TOPK_UPDATE(accA, mt);
            const ushort* pA = aptr + (size_t)(mt + 2) * 16 * CC;   // tail over-read: lands in Wgbf, unused
#pragma unroll
            for (int ks = 0; ks < 8; ks++) afA[ks] = *(const s16x8*)(pA + ks * 32);
            f32x4 accB = {0.f, 0.f, 0.f, 0.f};
            MFMA8(afB, accB);
            TOPK_UPDATE(accB, mt + 1);
        }
    }
    tkv[wave][pxl][g16 * 3 + 0] = v0; tki[wave][pxl][g16 * 3 + 0] = i0;
    tkv[wave][pxl][g16 * 3 + 1] = v1; tki[wave][pxl][g16 * 3 + 1] = i1;
    tkv[wave][pxl][g16 * 3 + 2] = v2; tki[wave][pxl][g16 * 3 + 2] = i2;
    __syncthreads();

    // ---- merge 12 -> top-4 candidates (every lane of the pixel computes same list) ----
    float c0 = -3e38f, c1 = -3e38f, c2 = -3e38f, c3 = -3e38f;
    int   d0 = 0, d1 = 0, d2 = 0, d3 = 0;
#pragma unroll
    for (int q = 0; q < 12; q++) {
        float s = tkv[wave][pxl][q];
        int m = tki[wave][pxl][q];
        if (s > c3) {
            if (s > c1) {
                if (s > c0) { c3 = c2; d3 = d2; c2 = c1; d2 = d1; c1 = c0; d1 = d0; c0 = s; d0 = m; }
                else        { c3 = c2; d3 = d2; c2 = c1; d2 = d1; c1 = s;  d1 = m; }
            } else {
                if (s > c2) { c3 = c2; d3 = d2; c2 = s;  d2 = m; }
                else        { c3 = s;  d3 = m; }
            }
        }
    }

    // ---- fp32 rescore: lane-group g rescores candidate g of its pixel (4-acc ILP) ----
    int cand = (g16 == 0) ? d0 : (g16 == 1) ? d1 : (g16 == 2) ? d2 : d3;
    {
        const float4* mr = (const float4*)(mem + (size_t)cand * CC);
        float sa = 0.f, sb = 0.f, sc2 = 0.f, sd = 0.f;
#pragma unroll 8
        for (int ci = 0; ci < 64; ci++) {
            float4 mv = mr[ci];
            sa = fmaf(Xs[ci * 4 + 0][pxw], mv.x, sa);
            sb = fmaf(Xs[ci * 4 + 1][pxw], mv.y, sb);
            sc2 = fmaf(Xs[ci * 4 + 2][pxw], mv.z, sc2);
            sd = fmaf(Xs[ci * 4 + 3][pxw], mv.w, sd);
        }
        rsv[wave][pxl][g16] = (sa + sb) + (sc2 + sd);
    }
    __syncthreads();

    // ---- top-2 of the 4 rescored (fp32) -> attention weights (per-lane regs) ----
    float s0 = -3e38f, s1 = -3e38f; int b0 = 0, b1 = 0;
#pragma unroll
    for (int q = 0; q < 4; q++) {
        float s = rsv[wave][pxl][q];
        int m = (q == 0) ? d0 : (q == 1) ? d1 : (q == 2) ? d2 : d3;
        if (s > s1) {
            if (s > s0) { s1 = s0; b1 = b0; s0 = s; b0 = m; }
            else        { s1 = s;  b1 = m; }
        }
    }
    float e = expf(s1 - s0);
    float a0 = 1.f / (1.f + e);
    float a1 = e * a0;

    // ---- phase B: x[o][px] fusion GEMM, double-buffered A prefetch + early epilogue loads
    {
        const ushort* wptr = Wgbf + (size_t)b * CC * CC + (size_t)pxl * CC + g16 * 8;
        s16x8 afA[8], afB[8];
#pragma unroll
        for (int ks = 0; ks < 8; ks++) afA[ks] = *(const s16x8*)(wptr + ks * 32);
#define PHASEB_TILE(AF, OT)                                                    \
    {                                                                          \
        int ob = (OT) * 16 + 4 * g16;                                          \
        float4 m0v = *(const float4*)(mf + (size_t)b0 * CC + ob);              \
        float4 m1v = *(const float4*)(mf + (size_t)b1 * CC + ob);              \
        float4 fbv = *(const float4*)(fb + ob);                                \
        f32x4 acc = {0.f, 0.f, 0.f, 0.f};                                      \
        MFMA8(AF, acc);                                                        \
        float vr0 = acc[0] + a0 * m0v.x + a1 * m1v.x + fbv.x;                  \
        float vr1 = acc[1] + a0 * m0v.y + a1 * m1v.y + fbv.y;                  \
        float vr2 = acc[2] + a0 * m0v.z + a1 * m1v.z + fbv.z;                  \
        float vr3 = acc[3] + a0 * m0v.w + a1 * m1v.w + fbv.w;                  \
        vr0 = vr0 > 0.f ? vr0 : 0.2f * vr0;                                    \
        vr1 = vr1 > 0.f ? vr1 : 0.2f * vr1;                                    \
        vr2 = vr2 > 0.f ? vr2 : 0.2f * vr2;                                    \
        vr3 = vr3 > 0.f ? vr3 : 0.2f * vr3;                                    \
        float* dst = xbuf + ((size_t)(b * CC + ob)) * HWHW + h * 64 + pxw;     \
        dst[0 * HWHW] = vr0; dst[1 * HWHW] = vr1;                              \
        dst[2 * HWHW] = vr2; dst[3 * HWHW] = vr3;                              \
    }
        for (int ot = 0; ot < 16; ot += 2) {
            const ushort* pB = wptr + (size_t)(ot + 1) * 16 * CC;
#pragma unroll
            for (int ks = 0; ks < 8; ks++) afB[ks] = *(const s16x8*)(pB + ks * 32);
            PHASEB_TILE(afA, ot);
            const ushort* pA = wptr + (size_t)(ot + 2) * 16 * CC;  // tail over-read: next-b rows / xb, unused
#pragma unroll
            for (int ks = 0; ks < 8; ks++) afA[ks] = *(const s16x8*)(pA + ks * 32);
            PHASEB_TILE(afB, ot + 1);
        }
    }
}

// ---------------- K7: depthwise dilated 3x3 (d=2) + bias + leaky ----------------
__global__ void k_dw(const float* __restrict__ x, const float* __restrict__ dw,
                     const float* __restrict__ db, float* __restrict__ out) {
    int bc = blockIdx.x;
    int c = bc & 255;
    __shared__ float plane[HWHW];
    const float4* src = (const float4*)(x + (size_t)bc * HWHW);
    int t = threadIdx.x;
#pragma unroll
    for (int k = 0; k < 4; k++) ((float4*)plane)[t + 256 * k] = src[t + 256 * k];
    __syncthreads();
    float w[9];
#pragma unroll
    for (int j = 0; j < 9; j++) w[j] = dw[c * 9 + j];
    float bias = db[c];
    float* dst = out + (size_t)bc * HWHW;
#pragma unroll
    for (int k = 0; k < 16; k++) {
        int p = t + 256 * k;
        int hh = p >> 6, ww = p & 63;
        float s = bias;
#pragma unroll
        for (int u = 0; u < 3; u++) {
            int h2 = hh + 2 * (u - 1);
            if ((unsigned)h2 < 64u) {
#pragma unroll
                for (int v = 0; v < 3; v++) {
                    int w2 = ww + 2 * (v - 1);
                    if ((unsigned)w2 < 64u) s = fmaf(plane[h2 * 64 + w2], w[u * 3 + v], s);
                }
            }
        }
        dst[p] = s > 0.f ? s : 0.2f * s;
    }
}

extern "C" void kernel_launch(void* const* d_in, const int* in_sizes, int n_in,
                              void* d_out, int out_size, void* d_ws, size_t ws_size,
                              hipStream_t stream) {
    const float* img = (const float*)d_in[0];
    const float* mem = (const float*)d_in[1];
    const float* fw  = (const float*)d_in[2];
    const float* fb  = (const float*)d_in[3];
    const float* dw  = (const float*)d_in[4];
    const float* db  = (const float*)d_in[5];
    float* out = (float*)d_out;
    float* ws = (float*)d_ws;

    float*  IG    = ws;                                   // 2048
    float*  gbuf  = ws + 2048;                            // 2048
    float*  mf    = ws + 4096;                            // 131072
    ushort* membf = (ushort*)(ws + 135168);               // 131072 u16
    ushort* Wgbf  = (ushort*)(ws + 135168 + 65536);       // 524288 u16
    float*  xb    = ws + 135168 + 65536 + 262144;         // 8388608 f32

    k_pre   <<<2240,    256, 0, stream>>>(img, mem, fw, IG, membf, mf);
    k_global<<<BB,      256, 0, stream>>>(IG, mem, gbuf);
    k_wgbf  <<<BB * CC, 256, 0, stream>>>(gbuf, fw, Wgbf);
    k_main  <<<BB * HH, 256, 0, stream>>>(img, mem, membf, Wgbf, mf, fb, xb);
    k_dw    <<<BB * CC, 256, 0, stream>>>(xb, dw, db, out);
}

// Round 5
// 218.792 us; speedup vs baseline: 1.2716x; 1.1896x over previous
//
#include <hip/hip_runtime.h>
#include <hip/hip_bf16.h>

#define BB 8
#define CC 256
#define HH 64
#define WW 64
#define MM 512
#define HWHW 4096

typedef __attribute__((ext_vector_type(4))) float f32x4;
typedef __attribute__((ext_vector_type(8))) short s16x8;

static __device__ __forceinline__ ushort f2bf(float f) {
    unsigned u = __float_as_uint(f);
    unsigned r = ((u >> 16) & 1u) + 0x7fffu;      // RNE
    return (ushort)((u + r) >> 16);
}

// ---------------- K_pre: fused {ig | prep | mf} ----------------
__global__ void k_pre(const float* __restrict__ img, const float* __restrict__ mem,
                      const float* __restrict__ fw, float* __restrict__ IG,
                      ushort* __restrict__ membf, float* __restrict__ mf) {
    int bid = blockIdx.x;
    int t = threadIdx.x;
    if (bid < 2048) {
        const float4* p = (const float4*)(img + (size_t)bid * HWHW);
        float s = 0.f;
#pragma unroll
        for (int k = 0; k < 4; k++) {
            float4 v = p[t + 256 * k];
            s += v.x + v.y + v.z + v.w;
        }
#pragma unroll
        for (int off = 32; off > 0; off >>= 1) s += __shfl_down(s, off);
        __shared__ float red[4];
        int wave = t >> 6, lane = t & 63;
        if (lane == 0) red[wave] = s;
        __syncthreads();
        if (t == 0) IG[bid] = (red[0] + red[1] + red[2] + red[3]) * (1.f / 4096.f);
    } else if (bid < 2176) {
        int i = ((bid - 2048) * 256 + t) * 4;
        float4 v = *(const float4*)(mem + i);
        ushort4 o;
        o.x = f2bf(v.x); o.y = f2bf(v.y); o.z = f2bf(v.z); o.w = f2bf(v.w);
        *(ushort4*)(membf + i) = o;
    } else {
        int m0 = (bid - 2176) * 8;
        __shared__ float mrow[8][CC];
#pragma unroll
        for (int j = 0; j < 8; j++) mrow[j][t] = mem[(size_t)(m0 + j) * CC + t];
        __syncthreads();
        const float4* fwr = (const float4*)(fw + (size_t)t * (2 * CC) + CC);
        float acc[8];
#pragma unroll
        for (int j = 0; j < 8; j++) acc[j] = 0.f;
#pragma unroll 8
        for (int ci = 0; ci < 64; ci++) {
            float4 fv = fwr[ci];
#pragma unroll
            for (int j = 0; j < 8; j++) {
                acc[j] = fmaf(mrow[j][ci * 4 + 0], fv.x, acc[j]);
                acc[j] = fmaf(mrow[j][ci * 4 + 1], fv.y, acc[j]);
                acc[j] = fmaf(mrow[j][ci * 4 + 2], fv.z, acc[j]);
                acc[j] = fmaf(mrow[j][ci * 4 + 3], fv.w, acc[j]);
            }
        }
#pragma unroll
        for (int j = 0; j < 8; j++) mf[(size_t)(m0 + j) * CC + t] = acc[j];
    }
}

// ---------------- K2: gate g = sigmoid(softmax(IG@M^T)@M + IG) ----------------
__global__ void k_global(const float* __restrict__ IG, const float* __restrict__ mem,
                         float* __restrict__ g) {
    int b = blockIdx.x;
    int t = threadIdx.x;
    __shared__ float ig[CC];
    __shared__ float sc[MM];
    __shared__ float red[256];
    ig[t] = IG[b * CC + t];
    __syncthreads();
#pragma unroll
    for (int half = 0; half < 2; half++) {
        int m = t + half * 256;
        const float4* mr = (const float4*)(mem + (size_t)m * CC);
        const float4* igr = (const float4*)ig;
        float s0 = 0.f, s1 = 0.f, s2 = 0.f, s3 = 0.f;
#pragma unroll 8
        for (int ci = 0; ci < 64; ci++) {
            float4 mv = mr[ci];
            float4 iv = igr[ci];
            s0 = fmaf(mv.x, iv.x, s0); s1 = fmaf(mv.y, iv.y, s1);
            s2 = fmaf(mv.z, iv.z, s2); s3 = fmaf(mv.w, iv.w, s3);
        }
        sc[m] = (s0 + s1) + (s2 + s3);
    }
    __syncthreads();
    red[t] = fmaxf(sc[t], sc[t + 256]);
    __syncthreads();
    for (int o = 128; o > 0; o >>= 1) {
        if (t < o) red[t] = fmaxf(red[t], red[t + o]);
        __syncthreads();
    }
    float mx = red[0];
    __syncthreads();
    float e0 = expf(sc[t] - mx), e1 = expf(sc[t + 256] - mx);
    red[t] = e0 + e1;
    __syncthreads();
    for (int o = 128; o > 0; o >>= 1) {
        if (t < o) red[t] += red[t + o];
        __syncthreads();
    }
    float inv = 1.f / red[0];
    sc[t] = e0 * inv; sc[t + 256] = e1 * inv;
    __syncthreads();
    float r0 = ig[t], r1 = 0.f, r2 = 0.f, r3 = 0.f;
#pragma unroll 8
    for (int m = 0; m < MM; m += 4) {
        r0 = fmaf(sc[m + 0], mem[(size_t)(m + 0) * CC + t], r0);
        r1 = fmaf(sc[m + 1], mem[(size_t)(m + 1) * CC + t], r1);
        r2 = fmaf(sc[m + 2], mem[(size_t)(m + 2) * CC + t], r2);
        r3 = fmaf(sc[m + 3], mem[(size_t)(m + 3) * CC + t], r3);
    }
    float r = (r0 + r1) + (r2 + r3);
    g[b * CC + t] = 1.f / (1.f + expf(-r));
}

// ---------------- K5: Wgbf[b][o][c] = bf16(g[b][c] * fusion_w[o][c]) ----------------
__global__ void k_wgbf(const float* __restrict__ g, const float* __restrict__ fw,
                       ushort* __restrict__ Wgbf) {
    int b = blockIdx.x >> 8, o = blockIdx.x & 255;
    int c = threadIdx.x;
    Wgbf[((size_t)blockIdx.x << 8) + c] = f2bf(g[(b << 8) + c] * fw[o * (2 * CC) + c]);
}

// ---------------- K6: main fused kernel (MFMA + LDS-staged A, 2-phase pipeline) ----
// grid 512 = B*H ; block 256 (4 waves); one image row (64 px) per block.
// 12 tiles of 64 rows: tiles 0..7 = membf (scores), 8..11 = Wgbf[b] (fusion).
// Reg-stage: 8x dwordx4/thread (linear, coalesced) -> ds_write_b128 at
// XOR-swizzled addr (colb ^ ((row&31)<<4)); reads use the same XOR (rule 21 OK:
// swizzle on LDS write+read, global stays linear). Double-buffered, 1 barrier/tile.
// k-mapping: lane-group g16 holds k=ks*32+8*g16..+8 (same bijection on A and B);
// C/D: col=lane&15, row=4*(lane>>4)+reg [verified].
__global__ __launch_bounds__(256, 1) void k_main(
        const float* __restrict__ img, const float* __restrict__ mem,
        const ushort* __restrict__ membf, const ushort* __restrict__ Wgbf,
        const float* __restrict__ mf, const float* __restrict__ fb,
        float* __restrict__ xbuf) {
    int bh = blockIdx.x;
    int b = bh >> 6, h = bh & 63;
    int t = threadIdx.x;
    int wave = __builtin_amdgcn_readfirstlane(t) >> 6;
    int lane = t & 63;
    int pxl  = lane & 15;
    int g16  = lane >> 4;
    int pxw  = wave * 16 + pxl;

    __shared__ __align__(16) float Xs[CC][64];      // 64 KB
    __shared__ __align__(16) char  As[2][32768];    // 64 KB A-tile double buffer
    __shared__ float tkv[4][16][12];
    __shared__ int   tki[4][16][12];
    __shared__ float rsv[4][16][4];

    const char* mem_b = (const char*)membf;                    // tiles 0..7
    const char* wg_b  = (const char*)Wgbf + (size_t)b * 131072; // tiles 8..11

    s16x8 R[8];
#define TSRC(TI) ((TI) < 8 ? mem_b + (size_t)(TI) * 32768 : wg_b + (size_t)((TI) - 8) * 32768)
#define LOAD8(TI)                                                              \
    { const char* gb = TSRC(TI);                                               \
      _Pragma("unroll")                                                        \
      for (int j = 0; j < 8; j++) {                                            \
          int row = j * 8 + (t >> 5); int colb = (t & 31) * 16;                \
          R[j] = *(const s16x8*)(gb + row * 512 + colb);                       \
      } }
#define DSW8(BUF)                                                              \
    { char* lb = As[BUF];                                                      \
      _Pragma("unroll")                                                        \
      for (int j = 0; j < 8; j++) {                                            \
          int row = j * 8 + (t >> 5); int colb = (t & 31) * 16;                \
          *(s16x8*)(lb + row * 512 + (colb ^ ((row & 31) << 4))) = R[j];       \
      } }
#define RD_A(LB, ROW, KS)                                                      \
    (*(const s16x8*)((LB) + (ROW) * 512 +                                      \
                     ((g16 * 16 + (KS) * 64) ^ (((ROW) & 31) << 4))))
#define MFMA_(A, B_, C_) __builtin_amdgcn_mfma_f32_16x16x32_bf16((A), (B_), (C_), 0, 0, 0)
#define TOPK_UPDATE(ACC, MB)                                                   \
    { _Pragma("unroll")                                                        \
      for (int r = 0; r < 4; r++) {                                            \
          float s = (ACC)[r]; int m = (MB) + r;                                \
          if (s > v2) {                                                        \
              if (s > v1) {                                                    \
                  if (s > v0) { v2 = v1; i2 = i1; v1 = v0; i1 = i0;            \
                                v0 = s;  i0 = m; }                             \
                  else        { v2 = v1; i2 = i1; v1 = s;  i1 = m; }           \
              } else          { v2 = s;  i2 = m; }                             \
          } } }

    // ---- prologue: issue tile0 loads, stage Xs, write tile0, load tile1 ----
    LOAD8(0);
    const float* src = img + (size_t)b * CC * HWHW + h * 64;
#pragma unroll
    for (int pass = 0; pass < 16; pass++) {
        int c = pass * 16 + (t >> 4);
        int w4 = (t & 15) * 4;
        *(float4*)&Xs[c][w4] = *(const float4*)(src + (size_t)c * HWHW + w4);
    }
    DSW8(0);
    LOAD8(1);
    __syncthreads();

    // ---- bf16 B-fragments for this wave's 16 pixels ----
    s16x8 bfr[8];
#pragma unroll
    for (int ks = 0; ks < 8; ks++) {
        s16x8 v;
#pragma unroll
        for (int j = 0; j < 8; j++)
            v[j] = (short)f2bf(Xs[ks * 32 + g16 * 8 + j][pxw]);
        bfr[ks] = v;
    }

    float v0 = -3e38f, v1 = -3e38f, v2 = -3e38f;
    int   i0 = 0, i1 = 0, i2 = 0;
    float a0 = 0.f, a1 = 0.f;
    int   b0 = 0, b1 = 0;
    int buf = 0;

    for (int tt = 0; tt < 12; tt++) {
        if (tt < 11) DSW8(buf ^ 1);          // stage tile tt+1 into other buffer
        if (tt < 10) LOAD8(tt + 2);          // issue loads for tile tt+2

        if (tt == 8) {
            // ---- phase-A wrap-up: publish per-lane top3, merge 12->4, fp32 rescore ----
            tkv[wave][pxl][g16 * 3 + 0] = v0; tki[wave][pxl][g16 * 3 + 0] = i0;
            tkv[wave][pxl][g16 * 3 + 1] = v1; tki[wave][pxl][g16 * 3 + 1] = i1;
            tkv[wave][pxl][g16 * 3 + 2] = v2; tki[wave][pxl][g16 * 3 + 2] = i2;
            __syncthreads();
            float c0 = -3e38f, c1 = -3e38f, c2 = -3e38f, c3 = -3e38f;
            int   d0 = 0, d1 = 0, d2 = 0, d3 = 0;
#pragma unroll
            for (int q = 0; q < 12; q++) {
                float s = tkv[wave][pxl][q];
                int m = tki[wave][pxl][q];
                if (s > c3) {
                    if (s > c1) {
                        if (s > c0) { c3 = c2; d3 = d2; c2 = c1; d2 = d1; c1 = c0; d1 = d0; c0 = s; d0 = m; }
                        else        { c3 = c2; d3 = d2; c2 = c1; d2 = d1; c1 = s;  d1 = m; }
                    } else {
                        if (s > c2) { c3 = c2; d3 = d2; c2 = s;  d2 = m; }
                        else        { c3 = s;  d3 = m; }
                    }
                }
            }
            int cand = (g16 == 0) ? d0 : (g16 == 1) ? d1 : (g16 == 2) ? d2 : d3;
            {
                const float4* mr = (const float4*)(mem + (size_t)cand * CC);
                float sa = 0.f, sb = 0.f, sc2 = 0.f, sd = 0.f;
#pragma unroll 8
                for (int ci = 0; ci < 64; ci++) {
                    float4 mv = mr[ci];
                    sa  = fmaf(Xs[ci * 4 + 0][pxw], mv.x, sa);
                    sb  = fmaf(Xs[ci * 4 + 1][pxw], mv.y, sb);
                    sc2 = fmaf(Xs[ci * 4 + 2][pxw], mv.z, sc2);
                    sd  = fmaf(Xs[ci * 4 + 3][pxw], mv.w, sd);
                }
                rsv[wave][pxl][g16] = (sa + sb) + (sc2 + sd);
            }
            __syncthreads();
            float s0 = -3e38f, s1 = -3e38f;
#pragma unroll
            for (int q = 0; q < 4; q++) {
                float s = rsv[wave][pxl][q];
                int m = (q == 0) ? d0 : (q == 1) ? d1 : (q == 2) ? d2 : d3;
                if (s > s1) {
                    if (s > s0) { s1 = s0; b1 = b0; s0 = s; b0 = m; }
                    else        { s1 = s;  b1 = m; }
                }
            }
            float e = expf(s1 - s0);
            a0 = 1.f / (1.f + e);
            a1 = e * a0;
        }

        const char* lb = As[buf];
        if (tt < 8) {
            // ---- scores tile: 4 sub-tiles as 2 independent-chain pairs ----
            int tbase = tt * 64;
#pragma unroll
            for (int sp = 0; sp < 2; sp++) {
                int r0 = sp * 32 + pxl, r1 = sp * 32 + 16 + pxl;
                s16x8 af0[8], af1[8];
#pragma unroll
                for (int ks = 0; ks < 8; ks++) {
                    af0[ks] = RD_A(lb, r0, ks);
                    af1[ks] = RD_A(lb, r1, ks);
                }
                f32x4 acc0 = {0.f, 0.f, 0.f, 0.f};
                f32x4 acc1 = {0.f, 0.f, 0.f, 0.f};
#pragma unroll
                for (int ks = 0; ks < 8; ks++) {
                    acc0 = MFMA_(af0[ks], bfr[ks], acc0);
                    acc1 = MFMA_(af1[ks], bfr[ks], acc1);
                }
                TOPK_UPDATE(acc0, tbase + sp * 32 + 4 * g16);
                TOPK_UPDATE(acc1, tbase + sp * 32 + 16 + 4 * g16);
            }
        } else {
            // ---- fusion tile: 4 sub-tiles, epilogue fused ----
            int u = tt - 8;
#pragma unroll
            for (int sp = 0; sp < 2; sp++) {
                int r0 = sp * 32 + pxl, r1 = sp * 32 + 16 + pxl;
                s16x8 af0[8], af1[8];
#pragma unroll
                for (int ks = 0; ks < 8; ks++) {
                    af0[ks] = RD_A(lb, r0, ks);
                    af1[ks] = RD_A(lb, r1, ks);
                }
                f32x4 acc0 = {0.f, 0.f, 0.f, 0.f};
                f32x4 acc1 = {0.f, 0.f, 0.f, 0.f};
#pragma unroll
                for (int ks = 0; ks < 8; ks++) {
                    acc0 = MFMA_(af0[ks], bfr[ks], acc0);
                    acc1 = MFMA_(af1[ks], bfr[ks], acc1);
                }
#pragma unroll
                for (int half = 0; half < 2; half++) {
                    f32x4 acc = half ? acc1 : acc0;
                    int ob = u * 64 + sp * 32 + half * 16 + 4 * g16;
                    float4 m0v = *(const float4*)(mf + (size_t)b0 * CC + ob);
                    float4 m1v = *(const float4*)(mf + (size_t)b1 * CC + ob);
                    float4 fbv = *(const float4*)(fb + ob);
                    float vr0 = acc[0] + a0 * m0v.x + a1 * m1v.x + fbv.x;
                    float vr1 = acc[1] + a0 * m0v.y + a1 * m1v.y + fbv.y;
                    float vr2 = acc[2] + a0 * m0v.z + a1 * m1v.z + fbv.z;
                    float vr3 = acc[3] + a0 * m0v.w + a1 * m1v.w + fbv.w;
                    vr0 = vr0 > 0.f ? vr0 : 0.2f * vr0;
                    vr1 = vr1 > 0.f ? vr1 : 0.2f * vr1;
                    vr2 = vr2 > 0.f ? vr2 : 0.2f * vr2;
                    vr3 = vr3 > 0.f ? vr3 : 0.2f * vr3;
                    float* dst = xbuf + ((size_t)(b * CC + ob)) * HWHW + h * 64 + pxw;
                    dst[0 * HWHW] = vr0; dst[1 * HWHW] = vr1;
                    dst[2 * HWHW] = vr2; dst[3 * HWHW] = vr3;
                }
            }
        }
        __syncthreads();
        buf ^= 1;
    }
}

// ---------------- K7: depthwise dilated 3x3 (d=2) + bias + leaky ----------------
__global__ void k_dw(const float* __restrict__ x, const float* __restrict__ dw,
                     const float* __restrict__ db, float* __restrict__ out) {
    int bc = blockIdx.x;
    int c = bc & 255;
    __shared__ float plane[HWHW];
    const float4* src = (const float4*)(x + (size_t)bc * HWHW);
    int t = threadIdx.x;
#pragma unroll
    for (int k = 0; k < 4; k++) ((float4*)plane)[t + 256 * k] = src[t + 256 * k];
    __syncthreads();
    float w[9];
#pragma unroll
    for (int j = 0; j < 9; j++) w[j] = dw[c * 9 + j];
    float bias = db[c];
    float* dst = out + (size_t)bc * HWHW;
#pragma unroll
    for (int k = 0; k < 16; k++) {
        int p = t + 256 * k;
        int hh = p >> 6, ww = p & 63;
        float s = bias;
#pragma unroll
        for (int u = 0; u < 3; u++) {
            int h2 = hh + 2 * (u - 1);
            if ((unsigned)h2 < 64u) {
#pragma unroll
                for (int v = 0; v < 3; v++) {
                    int w2 = ww + 2 * (v - 1);
                    if ((unsigned)w2 < 64u) s = fmaf(plane[h2 * 64 + w2], w[u * 3 + v], s);
                }
            }
        }
        dst[p] = s > 0.f ? s : 0.2f * s;
    }
}

extern "C" void kernel_launch(void* const* d_in, const int* in_sizes, int n_in,
                              void* d_out, int out_size, void* d_ws, size_t ws_size,
                              hipStream_t stream) {
    const float* img = (const float*)d_in[0];
    const float* mem = (const float*)d_in[1];
    const float* fw  = (const float*)d_in[2];
    const float* fb  = (const float*)d_in[3];
    const float* dw  = (const float*)d_in[4];
    const float* db  = (const float*)d_in[5];
    float* out = (float*)d_out;
    float* ws = (float*)d_ws;

    float*  IG    = ws;                                   // 2048
    float*  gbuf  = ws + 2048;                            // 2048
    float*  mf    = ws + 4096;                            // 131072
    ushort* membf = (ushort*)(ws + 135168);               // 131072 u16
    ushort* Wgbf  = (ushort*)(ws + 135168 + 65536);       // 524288 u16
    float*  xb    = ws + 135168 + 65536 + 262144;         // 8388608 f32

    k_pre   <<<2240,    256, 0, stream>>>(img, mem, fw, IG, membf, mf);
    k_global<<<BB,      256, 0, stream>>>(IG, mem, gbuf);
    k_wgbf  <<<BB * CC, 256, 0, stream>>>(gbuf, fw, Wgbf);
    k_main  <<<BB * HH, 256, 0, stream>>>(img, mem, membf, Wgbf, mf, fb, xb);
    k_dw    <<<BB * CC, 256, 0, stream>>>(xb, dw, db, out);
}